// Round 7
// baseline (260.307 us; speedup 1.0000x reference)
//
#include <hip/hip_runtime.h>
#include <hip/hip_bf16.h>
#include <stdint.h>
#include <math.h>

typedef __bf16 bf16_t;
typedef __attribute__((ext_vector_type(8))) __bf16 bf16x8;
typedef __attribute__((ext_vector_type(4))) __bf16 bf16x4;
typedef __attribute__((ext_vector_type(4))) short short4_t;
typedef __attribute__((ext_vector_type(4))) float f32x4;

#define GLOBAL_AS(p) ((const __attribute__((address_space(1))) void*)(p))
#define LDS_AS(p)    ((__attribute__((address_space(3))) void*)(p))

// Problem constants
#define B_ 2
#define S_ 2048
#define D_ 1024
#define H_ 16
#define DK_ 64
#define SP_ 128

// Q pre-scale: (1/sqrt(64)) * log2(e) -> scores emerge in log2 units, so
// softmax is ONE v_exp_f32 per element.
#define QSCALE 0.1803368801111144f

static __device__ inline float fast_exp2(float x) {
#if __has_builtin(__builtin_amdgcn_exp2f)
    return __builtin_amdgcn_exp2f(x);
#else
    return __expf(x * 0.6931471805599453f);
#endif
}

// 16x16x16 bf16 MFMA (K=16): A/B = 2 VGPRs (4 bf16), C/D = 4 f32.
static __device__ inline f32x4 mfma16x16x16bf16(short4_t a, short4_t b, f32x4 c) {
#if __has_builtin(__builtin_amdgcn_mfma_f32_16x16x16bf16_1k)
    return __builtin_amdgcn_mfma_f32_16x16x16bf16_1k(a, b, c, 0, 0, 0);
#else
    asm volatile("v_mfma_f32_16x16x16_bf16 %0, %1, %2, %0" : "+v"(c) : "v"(a), "v"(b));
    return c;
#endif
}

struct WPtrs { const float* w[4]; bf16_t* o[4]; };

// ---------------------------------------------------------------------------
// prep: three independent jobs in one dispatch (unchanged, verified).
// ---------------------------------------------------------------------------
__global__ __launch_bounds__(256) void prep(
    const float* __restrict__ q, const float* __restrict__ k,
    const float* __restrict__ v,
    bf16_t* __restrict__ qo, bf16_t* __restrict__ ko, bf16_t* __restrict__ vo,
    WPtrs wp, const float* __restrict__ phys, const float* __restrict__ Pw,
    float* __restrict__ PP) {
    int bx = blockIdx.x, tid = threadIdx.x;
    if (bx < 6144) {
        int z = bx >> 11, blk = bx & 2047;
        const float* in = (z == 0) ? q : (z == 1) ? k : v;
        bf16_t* out = (z == 0) ? qo : (z == 1) ? ko : vo;
        size_t i = ((size_t)blk * 256 + tid) * 8;
        f32x4 a = *(const f32x4*)(in + i);
        f32x4 b = *(const f32x4*)(in + i + 4);
        bf16x8 o;
#pragma unroll
        for (int e = 0; e < 4; ++e) { o[e] = (bf16_t)a[e]; o[4 + e] = (bf16_t)b[e]; }
        *(bf16x8*)(out + i) = o;
    } else if (bx < 10240) {
        __shared__ bf16_t t[32][33];
        int idx = bx - 6144;
        int z = idx >> 10;
        const float* W = wp.w[z];
        bf16_t* Wt = wp.o[z];
        int gx = (idx & 31) * 32, gy = ((idx >> 5) & 31) * 32;
        int x = tid & 31, y0 = tid >> 5;   // 32 x 8
#pragma unroll
        for (int j = 0; j < 32; j += 8)
            t[y0 + j][x] = (bf16_t)W[(size_t)(gy + y0 + j) * D_ + gx + x];
        __syncthreads();
#pragma unroll
        for (int j = 0; j < 32; j += 8)
            Wt[(size_t)(gx + y0 + j) * D_ + gy + x] = t[x][y0 + j];
    } else {
        int i = (bx - 10240) * 256 + tid;   // B*SP*D = 262144
        int n = i & (D_ - 1);
        int sb = i >> 10;
        float acc = 0.f;
#pragma unroll
        for (int p = 0; p < 3; ++p)
            acc += phys[sb * 3 + p] * Pw[p * D_ + n];
        PP[i] = acc;
    }
}

// ---------------------------------------------------------------------------
// Fused QKV projection GEMM (round-4 version: coalesced LDS-staged epilogue).
// grid (32, 8, 3), block 256. z=0: Q (scaled), z=1: K (+physics), z=2: V^T.
// ---------------------------------------------------------------------------
#define TSTR 272   // epilogue LDS tile row stride (256 data + 16 pad)

__global__ __launch_bounds__(256) void qkv_gemm(
    const bf16_t* __restrict__ Qi, const bf16_t* __restrict__ Ki,
    const bf16_t* __restrict__ Vi,
    const bf16_t* __restrict__ WqT, const bf16_t* __restrict__ WkT,
    const bf16_t* __restrict__ WvT,
    const float* __restrict__ bq, const float* __restrict__ bk,
    const float* __restrict__ bv,
    bf16_t* __restrict__ Qo, bf16_t* __restrict__ Ko, bf16_t* __restrict__ Vo,
    const float* __restrict__ PP, const float* __restrict__ pbp) {
    __shared__ alignas(16) char smem[40960];   // [0,16K) lA, [16K,32K) lB; epilogue tile [0,34816)
    bf16_t* lA = (bf16_t*)smem;
    bf16_t* lB = (bf16_t*)(smem + 16384);
    int z = blockIdx.z;
    const bf16_t* A = (z == 0) ? Qi : (z == 1) ? Ki : Vi;
    const bf16_t* Bt = (z == 0) ? WqT : (z == 1) ? WkT : WvT;
    const float* bias = (z == 0) ? bq : (z == 1) ? bk : bv;

    int tid = threadIdx.x;
    int lane = tid & 63, wid = tid >> 6;
    int quad = lane >> 4, l15 = lane & 15;
    int bm = blockIdx.x * 128;
    int bn = blockIdx.y * 128;
    int wm = (wid >> 1) * 64, wn = (wid & 1) * 64;
    f32x4 acc[4][4] = {};

    for (int k0 = 0; k0 < D_; k0 += 64) {
        __syncthreads();
        const char* gA = (const char*)(A + (size_t)bm * D_ + k0);
        const char* gB = (const char*)(Bt + (size_t)bn * D_ + k0);
#pragma unroll
        for (int j = 0; j < 4; ++j) {
            int woff = j * 4096 + wid * 1024;
            int fl = woff + lane * 16;
            int row = fl >> 7, col = fl & 127;
            __builtin_amdgcn_global_load_lds(GLOBAL_AS(gA + (size_t)row * (D_ * 2) + col),
                                             LDS_AS((char*)lA + woff), 16, 0, 0);
            __builtin_amdgcn_global_load_lds(GLOBAL_AS(gB + (size_t)row * (D_ * 2) + col),
                                             LDS_AS((char*)lB + woff), 16, 0, 0);
        }
        __syncthreads();
#pragma unroll
        for (int ks = 0; ks < 2; ++ks) {
            bf16x8 af[4], bfr[4];
#pragma unroll
            for (int i = 0; i < 4; ++i) {
                af[i] = *(const bf16x8*)((const char*)lA + (wm + i * 16 + l15) * 128 + ks * 64 + quad * 16);
                bfr[i] = *(const bf16x8*)((const char*)lB + (wn + i * 16 + l15) * 128 + ks * 64 + quad * 16);
            }
#pragma unroll
            for (int i = 0; i < 4; ++i)
#pragma unroll
                for (int j = 0; j < 4; ++j)
                    acc[i][j] = __builtin_amdgcn_mfma_f32_16x16x32_bf16(af[i], bfr[j], acc[i][j], 0, 0, 0);
        }
    }

    // ---- epilogue: bias/scale/physics in regs -> LDS tile -> coalesced stores
    __syncthreads();                           // all lA/lB reads retired
    float pb0 = (z == 1) ? pbp[0] : 0.f;
    char* T = smem;
#pragma unroll
    for (int i = 0; i < 4; ++i)
#pragma unroll
        for (int j = 0; j < 4; ++j) {
            int rl0 = wm + i * 16 + quad * 4;      // local row (m / s-dir)
            int c = wn + j * 16 + l15;             // local col (n-dir)
            float bv_ = bias[bn + c];
            if (z == 2) {
                // transpose in LDS: T[c][r] so global store is contiguous in s
                bf16x4 t4;
#pragma unroll
                for (int reg = 0; reg < 4; ++reg) t4[reg] = (bf16_t)(acc[i][j][reg] + bv_);
                *(bf16x4*)(T + c * TSTR + rl0 * 2) = t4;
            } else if (z == 1) {
#pragma unroll
                for (int reg = 0; reg < 4; ++reg) {
                    int r = bm + rl0 + reg;
                    int b = r >> 11, s = r & (S_ - 1);
                    float v = acc[i][j][reg] + bv_ +
                              pb0 * PP[((size_t)(b * SP_ + (s >> 4)) << 10) + ((s & 15) << 6) + ((bn + c) & 63)];
                    *(bf16_t*)(T + (rl0 + reg) * TSTR + c * 2) = (bf16_t)v;
                }
            } else {
#pragma unroll
                for (int reg = 0; reg < 4; ++reg)
                    *(bf16_t*)(T + (rl0 + reg) * TSTR + c * 2) = (bf16_t)((acc[i][j][reg] + bv_) * QSCALE);
            }
        }
    __syncthreads();
    if (z == 2) {
        int b = bm >> 11, s0 = bm & (S_ - 1);
        char* gout = (char*)Vo + (((size_t)(b << 10) + bn) * S_ + s0) * 2;
#pragma unroll
        for (int it = 0; it < 8; ++it) {
            int chunk = it * 256 + tid;
            int row = chunk >> 4, c16 = chunk & 15;   // row = local n
            bf16x8 v = *(const bf16x8*)(T + row * TSTR + c16 * 16);
            *(bf16x8*)(gout + (size_t)row * (S_ * 2) + c16 * 16) = v;
        }
    } else {
        bf16_t* O = (z == 0) ? Qo : Ko;
        char* gout = (char*)(O + (size_t)bm * D_ + bn);
#pragma unroll
        for (int it = 0; it < 8; ++it) {
            int chunk = it * 256 + tid;
            int row = chunk >> 4, c16 = chunk & 15;   // row = local m
            bf16x8 v = *(const bf16x8*)(T + row * TSTR + c16 * 16);
            *(bf16x8*)(gout + (size_t)row * (D_ * 2) + c16 * 16) = v;
        }
    }
}

// ---------------------------------------------------------------------------
// Flash attention — KVBLK=256: stage TWO 128-key tiles per phase.
// 256 threads (4 waves x 32 q: the LDS-efficient shape — r6's 16 q/wave
// doubled per-CU LDS traffic for nothing). 8 phases x {write staged regs ->
// barrier -> issue next 32KB prefetch -> compute 2 sub-tiles -> barrier}.
// Barriers 32 -> 18 per block; prefetch latency cover ~2x. LDS 70.7KB,
// 2 blocks/CU preserved (grid 512). XCD decode kept (FETCH 12MB proven).
// Qb pre-scaled by QSCALE; p = 2^s softmax (normalization-invariant).
// ---------------------------------------------------------------------------
#define KSTR 144    // lK row stride bytes (128 data + 16 pad), 256 rows
#define VSTR2 528   // lV row stride bytes (512 data + 16 pad), 64 rows

__global__ __launch_bounds__(256) void flash_attn(const bf16_t* Qb,
                                                  const bf16_t* __restrict__ Kb,
                                                  const bf16_t* __restrict__ Vt,
                                                  bf16_t* Ctx) {
    __shared__ alignas(16) char lK[256 * KSTR];   // [key][dk] / Q staging / lO
    __shared__ alignas(16) char lV[64 * VSTR2];   // [d][key 512B]
    int tid = threadIdx.x, lane = tid & 63, wid = tid >> 6;
    int quad = lane >> 4, l15 = lane & 15;

    // XCD decode: all 16 q-tiles of one (h,b) share an XCD (bid&7 = xcd)
    int bid = blockIdx.x;
    int xcd = bid & 7, slot = bid >> 3;
    int yz = xcd * 4 + (slot >> 4);           // 0..31 (h,b combined)
    int q0 = (slot & 15) * 128;
    int h = yz & 15, b = yz >> 4;

    const bf16_t* Qh = Qb + ((size_t)b * S_) * D_ + h * DK_;
    const bf16_t* Kh = Kb + ((size_t)b * S_) * D_ + h * DK_;
    const bf16_t* Vh = Vt + ((size_t)b * D_ + h * DK_) * S_;

    // ---- stage Q (16KB) into lK rows 0..127, read per-wave frags ----
    {
        const char* g = (const char*)(Qh + (size_t)q0 * D_);
#pragma unroll
        for (int j = 0; j < 4; ++j) {
            int flat = j * 4096 + tid * 16;
            bf16x8 v = *(const bf16x8*)(g + (size_t)(flat >> 7) * (D_ * 2) + (flat & 127));
            *(bf16x8*)(lK + (flat >> 7) * KSTR + (flat & 127)) = v;
        }
    }
    __syncthreads();
    bf16x8 qf[2][2];   // [mt][ks]: B[n=q=l15][dk=ks*32+quad*8+j]
#pragma unroll
    for (int mt = 0; mt < 2; ++mt)
#pragma unroll
        for (int ks = 0; ks < 2; ++ks)
            qf[mt][ks] = *(const bf16x8*)(lK + (wid * 32 + mt * 16 + l15) * KSTR + ks * 64 + quad * 16);
    // within-wave LDS ops are in-order (read before the coming write);
    // cross-wave safety via this barrier.
    __syncthreads();

    f32x4 ot[4][2] = {};            // O^T[d-tile][q-tile]
    float l_i[2] = {0.f, 0.f};

    // prefetch registers: one 256-key phase = K 32KB + V 32KB (128B each/thr)
    bf16x8 vk[8], vv[8];
    const int NP = S_ / 256;        // 8 phases
    {
        const char* gK = (const char*)Kh;
        const char* gV = (const char*)Vh;
#pragma unroll
        for (int j = 0; j < 8; ++j) {
            int fk = j * 4096 + tid * 16;
            vk[j] = *(const bf16x8*)(gK + (size_t)(fk >> 7) * (D_ * 2) + (fk & 127));
            vv[j] = *(const bf16x8*)(gV + (size_t)(fk >> 9) * (S_ * 2) + (fk & 511));
        }
    }

    for (int t = 0; t < NP; ++t) {
        // write phase t from regs to LDS
#pragma unroll
        for (int j = 0; j < 8; ++j) {
            int fk = j * 4096 + tid * 16;
            *(bf16x8*)(lK + (fk >> 7) * KSTR + (fk & 127)) = vk[j];
            *(bf16x8*)(lV + (fk >> 9) * VSTR2 + (fk & 511)) = vv[j];
        }
        __syncthreads();

        // issue-early loads for phase t+1 (consumed at next write phase)
        if (t + 1 < NP) {
            const char* gK = (const char*)(Kh + (size_t)(t + 1) * 256 * D_);
            const char* gV = (const char*)(Vh + (size_t)(t + 1) * 256);
#pragma unroll
            for (int j = 0; j < 8; ++j) {
                int fk = j * 4096 + tid * 16;
                vk[j] = *(const bf16x8*)(gK + (size_t)(fk >> 7) * (D_ * 2) + (fk & 127));
                vv[j] = *(const bf16x8*)(gV + (size_t)(fk >> 9) * (S_ * 2) + (fk & 511));
            }
        }

        // two 128-key sub-tiles
#pragma unroll
        for (int kk = 0; kk < 2; ++kk) {
            // St = K·Q^T  (log2-domain scores)
            f32x4 sc[8][2];
#pragma unroll
            for (int kt = 0; kt < 8; ++kt)
#pragma unroll
                for (int mt = 0; mt < 2; ++mt) sc[kt][mt] = (f32x4){0.f, 0.f, 0.f, 0.f};
            __builtin_amdgcn_s_setprio(1);
#pragma unroll
            for (int kt = 0; kt < 8; ++kt) {
                int row = kk * 128 + kt * 16 + l15;
                bf16x8 kf0 = *(const bf16x8*)(lK + row * KSTR + quad * 16);
                bf16x8 kf1 = *(const bf16x8*)(lK + row * KSTR + 64 + quad * 16);
#pragma unroll
                for (int mt = 0; mt < 2; ++mt) {
                    sc[kt][mt] = __builtin_amdgcn_mfma_f32_16x16x32_bf16(kf0, qf[mt][0], sc[kt][mt], 0, 0, 0);
                    sc[kt][mt] = __builtin_amdgcn_mfma_f32_16x16x32_bf16(kf1, qf[mt][1], sc[kt][mt], 0, 0, 0);
                }
            }
            __builtin_amdgcn_s_setprio(0);

            // softmax numerator: p = 2^s; accumulate l
#pragma unroll
            for (int mt = 0; mt < 2; ++mt) {
                float rsum = 0.f;
#pragma unroll
                for (int kt = 0; kt < 8; ++kt)
#pragma unroll
                    for (int r = 0; r < 4; ++r) {
                        float p = fast_exp2(sc[kt][mt][r]);
                        sc[kt][mt][r] = p;
                        rsum += p;
                    }
                rsum += __shfl_xor(rsum, 16, 64);
                rsum += __shfl_xor(rsum, 32, 64);
                l_i[mt] += rsum;
            }

            // PV: O^T += V^T·P^T, 16x16x16, P direct from registers
            __builtin_amdgcn_s_setprio(1);
#pragma unroll
            for (int kt = 0; kt < 8; ++kt) {
                short4_t bp[2];
#pragma unroll
                for (int mt = 0; mt < 2; ++mt) {
                    bf16x4 t4;
#pragma unroll
                    for (int r = 0; r < 4; ++r) t4[r] = (bf16_t)sc[kt][mt][r];
                    bp[mt] = *(short4_t*)&t4;
                }
#pragma unroll
                for (int dt = 0; dt < 4; ++dt) {
                    bf16x4 a4 = *(const bf16x4*)(lV + (dt * 16 + l15) * VSTR2 +
                                                 kk * 256 + kt * 32 + quad * 8);
                    short4_t ap = *(short4_t*)&a4;
#pragma unroll
                    for (int mt = 0; mt < 2; ++mt)
                        ot[dt][mt] = mfma16x16x16bf16(ap, bp[mt], ot[dt][mt]);
                }
            }
            __builtin_amdgcn_s_setprio(0);
        }
        __syncthreads();   // compute reads done before next write phase
    }

    // epilogue: O^T -> O via padded LDS, coalesced 16B writes
#pragma unroll
    for (int mt = 0; mt < 2; ++mt) {
        float inv_l = 1.0f / l_i[mt];
#pragma unroll
        for (int dt = 0; dt < 4; ++dt) {
            bf16x4 t4;
#pragma unroll
            for (int r = 0; r < 4; ++r) t4[r] = (bf16_t)(ot[dt][mt][r] * inv_l);
            *(bf16x4*)(lK + (wid * 32 + mt * 16 + l15) * KSTR + dt * 32 + quad * 8) = t4;
        }
    }
    __syncthreads();
    {
        char* gout = (char*)(Ctx + ((size_t)b * S_ + q0) * D_ + h * DK_);
#pragma unroll
        for (int j = 0; j < 4; ++j) {
            int flat = j * 4096 + tid * 16;
            bf16x8 v = *(const bf16x8*)(lK + (flat >> 7) * KSTR + (flat & 127));
            *(bf16x8*)(gout + (size_t)(flat >> 7) * (D_ * 2) + (flat & 127)) = v;
        }
    }
}

// ---------------------------------------------------------------------------
// Output GEMM with global_load_lds staging (unchanged, verified).
// ---------------------------------------------------------------------------
__global__ __launch_bounds__(256) void gemm_out(const bf16_t* __restrict__ A,
                                                const bf16_t* __restrict__ Bt,
                                                const float* __restrict__ bias,
                                                float* __restrict__ C) {
    __shared__ alignas(16) bf16_t lA[128 * 64];
    __shared__ alignas(16) bf16_t lB[128 * 64];
    int tid = threadIdx.x;
    int lane = tid & 63, wid = tid >> 6;
    int quad = lane >> 4, l15 = lane & 15;
    int bm = blockIdx.x * 128;
    int bn = blockIdx.y * 128;
    int wm = (wid >> 1) * 64, wn = (wid & 1) * 64;
    f32x4 acc[4][4] = {};

    for (int k0 = 0; k0 < D_; k0 += 64) {
        __syncthreads();
        const char* gA = (const char*)(A + (size_t)bm * D_ + k0);
        const char* gB = (const char*)(Bt + (size_t)bn * D_ + k0);
#pragma unroll
        for (int j = 0; j < 4; ++j) {
            int woff = j * 4096 + wid * 1024;
            int fl = woff + lane * 16;
            int row = fl >> 7, col = fl & 127;
            __builtin_amdgcn_global_load_lds(GLOBAL_AS(gA + (size_t)row * (D_ * 2) + col),
                                             LDS_AS((char*)lA + woff), 16, 0, 0);
            __builtin_amdgcn_global_load_lds(GLOBAL_AS(gB + (size_t)row * (D_ * 2) + col),
                                             LDS_AS((char*)lB + woff), 16, 0, 0);
        }
        __syncthreads();
#pragma unroll
        for (int ks = 0; ks < 2; ++ks) {
            bf16x8 af[4], bfr[4];
#pragma unroll
            for (int i = 0; i < 4; ++i) {
                af[i] = *(const bf16x8*)((const char*)lA + (wm + i * 16 + l15) * 128 + ks * 64 + quad * 16);
                bfr[i] = *(const bf16x8*)((const char*)lB + (wn + i * 16 + l15) * 128 + ks * 64 + quad * 16);
            }
#pragma unroll
            for (int i = 0; i < 4; ++i)
#pragma unroll
                for (int j = 0; j < 4; ++j)
                    acc[i][j] = __builtin_amdgcn_mfma_f32_16x16x32_bf16(af[i], bfr[j], acc[i][j], 0, 0, 0);
        }
    }
#pragma unroll
    for (int i = 0; i < 4; ++i)
#pragma unroll
        for (int j = 0; j < 4; ++j) {
            int r0 = bm + wm + i * 16 + quad * 4;
            int c = bn + wn + j * 16 + l15;
            float bv_ = bias[c];
#pragma unroll
            for (int reg = 0; reg < 4; ++reg)
                C[(size_t)(r0 + reg) * D_ + c] = acc[i][j][reg] + bv_;
        }
}

// ---------------------------------------------------------------------------
// Workspace (41 MB): layout unchanged.
// ---------------------------------------------------------------------------
extern "C" void kernel_launch(void* const* d_in, const int* in_sizes, int n_in,
                              void* d_out, int out_size, void* d_ws, size_t ws_size,
                              hipStream_t stream) {
    const float* query  = (const float*)d_in[0];
    const float* key_in = (const float*)d_in[1];
    const float* value  = (const float*)d_in[2];
    const float* phys   = (const float*)d_in[3];
    const float* Wq     = (const float*)d_in[4];
    const float* bq     = (const float*)d_in[5];
    const float* Wk     = (const float*)d_in[6];
    const float* bk     = (const float*)d_in[7];
    const float* Wv     = (const float*)d_in[8];
    const float* bv     = (const float*)d_in[9];
    const float* Wo     = (const float*)d_in[10];
    const float* bo     = (const float*)d_in[11];
    const float* Pw     = (const float*)d_in[12];
    const float* pb     = (const float*)d_in[13];

    char* ws = (char*)d_ws;
    const size_t MB = 1ull << 20;
    bf16_t* Kb  = (bf16_t*)(ws + 0 * MB);
    bf16_t* QC  = (bf16_t*)(ws + 8 * MB);
    bf16_t* Kin = (bf16_t*)(ws + 16 * MB);
    bf16_t* Vin = (bf16_t*)(ws + 24 * MB);
    bf16_t* WqT = (bf16_t*)(ws + 32 * MB);
    bf16_t* WkT = (bf16_t*)(ws + 34 * MB);
    bf16_t* WvT = (bf16_t*)(ws + 36 * MB);
    bf16_t* WoT = (bf16_t*)(ws + 38 * MB);
    float*  PP  = (float*)(ws + 40 * MB);
    bf16_t* Vt  = (bf16_t*)d_out;                    // lo 8 MB
    bf16_t* Qin = (bf16_t*)((char*)d_out + 8 * MB);  // hi 8 MB

    WPtrs wp;
    wp.w[0] = Wq; wp.w[1] = Wk; wp.w[2] = Wv; wp.w[3] = Wo;
    wp.o[0] = WqT; wp.o[1] = WkT; wp.o[2] = WvT; wp.o[3] = WoT;

    prep<<<11264, 256, 0, stream>>>(query, key_in, value, Qin, Kin, Vin,
                                    wp, phys, Pw, PP);

    dim3 gq(32, 8, 3);
    qkv_gemm<<<gq, 256, 0, stream>>>(Qin, Kin, Vin, WqT, WkT, WvT,
                                     bq, bk, bv, QC, Kb, Vt, PP, pb);

    flash_attn<<<512, 256, 0, stream>>>(QC, Kb, Vt, QC);

    dim3 gg(32, 8);
    gemm_out<<<gg, 256, 0, stream>>>(QC, WoT, bo, (float*)d_out);
}

// Round 8
// 253.232 us; speedup vs baseline: 1.0279x; 1.0279x over previous
//
#include <hip/hip_runtime.h>
#include <hip/hip_bf16.h>
#include <stdint.h>
#include <math.h>

typedef __bf16 bf16_t;
typedef __attribute__((ext_vector_type(8))) __bf16 bf16x8;
typedef __attribute__((ext_vector_type(4))) __bf16 bf16x4;
typedef __attribute__((ext_vector_type(4))) short short4_t;
typedef __attribute__((ext_vector_type(4))) float f32x4;
typedef __attribute__((ext_vector_type(4))) unsigned int u32x4;

#define GLOBAL_AS(p) ((const __attribute__((address_space(1))) void*)(p))
#define LDS_AS(p)    ((__attribute__((address_space(3))) void*)(p))

// Problem constants
#define B_ 2
#define S_ 2048
#define D_ 1024
#define H_ 16
#define DK_ 64
#define SP_ 128

// Q pre-scale: (1/sqrt(64)) * log2(e) -> scores emerge in log2 units, so
// softmax is ONE v_exp_f32 per element.
#define QSCALE 0.1803368801111144f

static __device__ inline float fast_exp2(float x) {
#if __has_builtin(__builtin_amdgcn_exp2f)
    return __builtin_amdgcn_exp2f(x);
#else
    return __expf(x * 0.6931471805599453f);
#endif
}

struct WPtrs { const float* w[4]; bf16_t* o[4]; };

// ---------------------------------------------------------------------------
// prep: three independent jobs in one dispatch (unchanged, verified).
// ---------------------------------------------------------------------------
__global__ __launch_bounds__(256) void prep(
    const float* __restrict__ q, const float* __restrict__ k,
    const float* __restrict__ v,
    bf16_t* __restrict__ qo, bf16_t* __restrict__ ko, bf16_t* __restrict__ vo,
    WPtrs wp, const float* __restrict__ phys, const float* __restrict__ Pw,
    float* __restrict__ PP) {
    int bx = blockIdx.x, tid = threadIdx.x;
    if (bx < 6144) {
        int z = bx >> 11, blk = bx & 2047;
        const float* in = (z == 0) ? q : (z == 1) ? k : v;
        bf16_t* out = (z == 0) ? qo : (z == 1) ? ko : vo;
        size_t i = ((size_t)blk * 256 + tid) * 8;
        f32x4 a = *(const f32x4*)(in + i);
        f32x4 b = *(const f32x4*)(in + i + 4);
        bf16x8 o;
#pragma unroll
        for (int e = 0; e < 4; ++e) { o[e] = (bf16_t)a[e]; o[4 + e] = (bf16_t)b[e]; }
        *(bf16x8*)(out + i) = o;
    } else if (bx < 10240) {
        __shared__ bf16_t t[32][33];
        int idx = bx - 6144;
        int z = idx >> 10;
        const float* W = wp.w[z];
        bf16_t* Wt = wp.o[z];
        int gx = (idx & 31) * 32, gy = ((idx >> 5) & 31) * 32;
        int x = tid & 31, y0 = tid >> 5;   // 32 x 8
#pragma unroll
        for (int j = 0; j < 32; j += 8)
            t[y0 + j][x] = (bf16_t)W[(size_t)(gy + y0 + j) * D_ + gx + x];
        __syncthreads();
#pragma unroll
        for (int j = 0; j < 32; j += 8)
            Wt[(size_t)(gx + y0 + j) * D_ + gy + x] = t[x][y0 + j];
    } else {
        int i = (bx - 10240) * 256 + tid;   // B*SP*D = 262144
        int n = i & (D_ - 1);
        int sb = i >> 10;
        float acc = 0.f;
#pragma unroll
        for (int p = 0; p < 3; ++p)
            acc += phys[sb * 3 + p] * Pw[p * D_ + n];
        PP[i] = acc;
    }
}

// ---------------------------------------------------------------------------
// Fused QKV projection GEMM (round-4 version: coalesced LDS-staged epilogue).
// grid (32, 8, 3), block 256. z=0: Q (scaled), z=1: K (+physics), z=2: V^T.
// ---------------------------------------------------------------------------
#define TSTR 272   // epilogue LDS tile row stride (256 data + 16 pad)

__global__ __launch_bounds__(256) void qkv_gemm(
    const bf16_t* __restrict__ Qi, const bf16_t* __restrict__ Ki,
    const bf16_t* __restrict__ Vi,
    const bf16_t* __restrict__ WqT, const bf16_t* __restrict__ WkT,
    const bf16_t* __restrict__ WvT,
    const float* __restrict__ bq, const float* __restrict__ bk,
    const float* __restrict__ bv,
    bf16_t* __restrict__ Qo, bf16_t* __restrict__ Ko, bf16_t* __restrict__ Vo,
    const float* __restrict__ PP, const float* __restrict__ pbp) {
    __shared__ alignas(16) char smem[40960];   // [0,16K) lA, [16K,32K) lB; epilogue tile [0,34816)
    bf16_t* lA = (bf16_t*)smem;
    bf16_t* lB = (bf16_t*)(smem + 16384);
    int z = blockIdx.z;
    const bf16_t* A = (z == 0) ? Qi : (z == 1) ? Ki : Vi;
    const bf16_t* Bt = (z == 0) ? WqT : (z == 1) ? WkT : WvT;
    const float* bias = (z == 0) ? bq : (z == 1) ? bk : bv;

    int tid = threadIdx.x;
    int lane = tid & 63, wid = tid >> 6;
    int quad = lane >> 4, l15 = lane & 15;
    int bm = blockIdx.x * 128;
    int bn = blockIdx.y * 128;
    int wm = (wid >> 1) * 64, wn = (wid & 1) * 64;
    f32x4 acc[4][4] = {};

    for (int k0 = 0; k0 < D_; k0 += 64) {
        __syncthreads();
        const char* gA = (const char*)(A + (size_t)bm * D_ + k0);
        const char* gB = (const char*)(Bt + (size_t)bn * D_ + k0);
#pragma unroll
        for (int j = 0; j < 4; ++j) {
            int woff = j * 4096 + wid * 1024;
            int fl = woff + lane * 16;
            int row = fl >> 7, col = fl & 127;
            __builtin_amdgcn_global_load_lds(GLOBAL_AS(gA + (size_t)row * (D_ * 2) + col),
                                             LDS_AS((char*)lA + woff), 16, 0, 0);
            __builtin_amdgcn_global_load_lds(GLOBAL_AS(gB + (size_t)row * (D_ * 2) + col),
                                             LDS_AS((char*)lB + woff), 16, 0, 0);
        }
        __syncthreads();
#pragma unroll
        for (int ks = 0; ks < 2; ++ks) {
            bf16x8 af[4], bfr[4];
#pragma unroll
            for (int i = 0; i < 4; ++i) {
                af[i] = *(const bf16x8*)((const char*)lA + (wm + i * 16 + l15) * 128 + ks * 64 + quad * 16);
                bfr[i] = *(const bf16x8*)((const char*)lB + (wn + i * 16 + l15) * 128 + ks * 64 + quad * 16);
            }
#pragma unroll
            for (int i = 0; i < 4; ++i)
#pragma unroll
                for (int j = 0; j < 4; ++j)
                    acc[i][j] = __builtin_amdgcn_mfma_f32_16x16x32_bf16(af[i], bfr[j], acc[i][j], 0, 0, 0);
        }
    }

    // ---- epilogue: bias/scale/physics in regs -> LDS tile -> coalesced stores
    __syncthreads();                           // all lA/lB reads retired
    float pb0 = (z == 1) ? pbp[0] : 0.f;
    char* T = smem;
#pragma unroll
    for (int i = 0; i < 4; ++i)
#pragma unroll
        for (int j = 0; j < 4; ++j) {
            int rl0 = wm + i * 16 + quad * 4;      // local row (m / s-dir)
            int c = wn + j * 16 + l15;             // local col (n-dir)
            float bv_ = bias[bn + c];
            if (z == 2) {
                // transpose in LDS: T[c][r] so global store is contiguous in s
                bf16x4 t4;
#pragma unroll
                for (int reg = 0; reg < 4; ++reg) t4[reg] = (bf16_t)(acc[i][j][reg] + bv_);
                *(bf16x4*)(T + c * TSTR + rl0 * 2) = t4;
            } else if (z == 1) {
#pragma unroll
                for (int reg = 0; reg < 4; ++reg) {
                    int r = bm + rl0 + reg;
                    int b = r >> 11, s = r & (S_ - 1);
                    float v = acc[i][j][reg] + bv_ +
                              pb0 * PP[((size_t)(b * SP_ + (s >> 4)) << 10) + ((s & 15) << 6) + ((bn + c) & 63)];
                    *(bf16_t*)(T + (rl0 + reg) * TSTR + c * 2) = (bf16_t)v;
                }
            } else {
#pragma unroll
                for (int reg = 0; reg < 4; ++reg)
                    *(bf16_t*)(T + (rl0 + reg) * TSTR + c * 2) = (bf16_t)((acc[i][j][reg] + bv_) * QSCALE);
            }
        }
    __syncthreads();
    if (z == 2) {
        int b = bm >> 11, s0 = bm & (S_ - 1);
        char* gout = (char*)Vo + (((size_t)(b << 10) + bn) * S_ + s0) * 2;
#pragma unroll
        for (int it = 0; it < 8; ++it) {
            int chunk = it * 256 + tid;
            int row = chunk >> 4, c16 = chunk & 15;   // row = local n
            bf16x8 v = *(const bf16x8*)(T + row * TSTR + c16 * 16);
            *(bf16x8*)(gout + (size_t)row * (S_ * 2) + c16 * 16) = v;
        }
    } else {
        bf16_t* O = (z == 0) ? Qo : Ko;
        char* gout = (char*)(O + (size_t)bm * D_ + bn);
#pragma unroll
        for (int it = 0; it < 8; ++it) {
            int chunk = it * 256 + tid;
            int row = chunk >> 4, c16 = chunk & 15;   // row = local m
            bf16x8 v = *(const bf16x8*)(T + row * TSTR + c16 * 16);
            *(bf16x8*)(gout + (size_t)row * (D_ * 2) + c16 * 16) = v;
        }
    }
}

// ---------------------------------------------------------------------------
// Flash attention — r4 structure (62.0us baseline: 4 waves x 32 q, reg
// staging, padded LDS, 3D grid) with ONE change: PV uses 16x16x32 MFMA
// (K=32) instead of 64x 16x16x16 (K=16). The K=16 legacy op was 2/3 of the
// matrix-pipe issue slots at half FLOPs/inst. P-fragment repack for K=32
// B-layout (lane quad needs keys quad*8+0..7; QK C-layout gives quad keys
// kt*16+quad*4+r): v_cvt_pk_bf16_f32 pairs -> ds_bpermute cross-quad pull
// -> cndmask kt-half select (T12 mechanism). Derivation verified:
//   dest(q,l15) word{0,1}/{2,3} = w{0,1} of sc[2c+(q>=2)] from src lanes
//   2(q&1)*16+l15 and +16. A-frag = contiguous 16B from lV (bank-floor).
// ---------------------------------------------------------------------------
#define KSTR 144   // lK row stride bytes (128 data + 16 pad)
#define VSTR 272   // lV row stride bytes (256 data + 16 pad)

__global__ __launch_bounds__(256) void flash_attn(const bf16_t* Qb,
                                                  const bf16_t* __restrict__ Kb,
                                                  const bf16_t* __restrict__ Vt,
                                                  bf16_t* Ctx) {
    __shared__ alignas(16) char lK[128 * KSTR];   // [key][dk] / Q staging / lO
    __shared__ alignas(16) char lV[64 * VSTR];    // [d][key]
    int tid = threadIdx.x, lane = tid & 63, wid = tid >> 6;
    int quad = lane >> 4, l15 = lane & 15;
    int q0 = blockIdx.x * 128;
    int h = blockIdx.y, b = blockIdx.z;
    const bf16_t* Qh = Qb + ((size_t)b * S_) * D_ + h * DK_;
    const bf16_t* Kh = Kb + ((size_t)b * S_) * D_ + h * DK_;
    const bf16_t* Vh = Vt + ((size_t)b * D_ + h * DK_) * S_;

    {
        const char* g = (const char*)(Qh + (size_t)q0 * D_);
#pragma unroll
        for (int j = 0; j < 4; ++j) {
            int flat = j * 4096 + tid * 16;
            bf16x8 v = *(const bf16x8*)(g + (size_t)(flat >> 7) * (D_ * 2) + (flat & 127));
            *(bf16x8*)(lK + (flat >> 7) * KSTR + (flat & 127)) = v;
        }
    }
    __syncthreads();
    bf16x8 qf[2][2];   // [mt][ks]: B[n=q=l15][dk=ks*32+quad*8+j]
#pragma unroll
    for (int mt = 0; mt < 2; ++mt)
#pragma unroll
        for (int ks = 0; ks < 2; ++ks)
            qf[mt][ks] = *(const bf16x8*)(lK + (wid * 32 + mt * 16 + l15) * KSTR + ks * 64 + quad * 16);

    f32x4 ot[4][2] = {};            // O^T[d-tile][q-tile]
    float l_i[2] = {0.f, 0.f};

    for (int t = 0; t < S_ / 128; ++t) {
        const char* gK = (const char*)(Kh + (size_t)t * 128 * D_);
        const char* gV = (const char*)(Vh + (size_t)t * 128);
        bf16x8 vk[4], vv[4];
#pragma unroll
        for (int j = 0; j < 4; ++j) {
            int flat = j * 4096 + tid * 16;
            vk[j] = *(const bf16x8*)(gK + (size_t)(flat >> 7) * (D_ * 2) + (flat & 127));
            vv[j] = *(const bf16x8*)(gV + (size_t)(flat >> 8) * (S_ * 2) + (flat & 255));
        }
        __syncthreads();
#pragma unroll
        for (int j = 0; j < 4; ++j) {
            int flat = j * 4096 + tid * 16;
            *(bf16x8*)(lK + (flat >> 7) * KSTR + (flat & 127)) = vk[j];
            *(bf16x8*)(lV + (flat >> 8) * VSTR + (flat & 255)) = vv[j];
        }
        __syncthreads();

        // St = K·Q^T  (log2-domain scores)
        f32x4 sc[8][2];
#pragma unroll
        for (int kt = 0; kt < 8; ++kt)
#pragma unroll
            for (int mt = 0; mt < 2; ++mt) sc[kt][mt] = (f32x4){0.f, 0.f, 0.f, 0.f};
        __builtin_amdgcn_s_setprio(1);
#pragma unroll
        for (int kt = 0; kt < 8; ++kt) {
            bf16x8 kf0 = *(const bf16x8*)(lK + (kt * 16 + l15) * KSTR + quad * 16);
            bf16x8 kf1 = *(const bf16x8*)(lK + (kt * 16 + l15) * KSTR + 64 + quad * 16);
#pragma unroll
            for (int mt = 0; mt < 2; ++mt) {
                sc[kt][mt] = __builtin_amdgcn_mfma_f32_16x16x32_bf16(kf0, qf[mt][0], sc[kt][mt], 0, 0, 0);
                sc[kt][mt] = __builtin_amdgcn_mfma_f32_16x16x32_bf16(kf1, qf[mt][1], sc[kt][mt], 0, 0, 0);
            }
        }
        __builtin_amdgcn_s_setprio(0);

        // softmax numerator: p = 2^s (one v_exp_f32 each); accumulate l
#pragma unroll
        for (int mt = 0; mt < 2; ++mt) {
            float rsum = 0.f;
#pragma unroll
            for (int kt = 0; kt < 8; ++kt)
#pragma unroll
                for (int r = 0; r < 4; ++r) {
                    float p = fast_exp2(sc[kt][mt][r]);
                    sc[kt][mt][r] = p;
                    rsum += p;
                }
            rsum += __shfl_xor(rsum, 16, 64);
            rsum += __shfl_xor(rsum, 32, 64);
            l_i[mt] += rsum;
        }

        // PV: O^T += V^T·P^T via 16x16x32 (K=32). P repacked to B-frag
        // layout (lane quad holds keys quad*8+0..7 of 32-key slice c).
        __builtin_amdgcn_s_setprio(1);
#pragma unroll
        for (int c = 0; c < 4; ++c) {
            u32x4 bpv[2];
#pragma unroll
            for (int mt = 0; mt < 2; ++mt) {
                unsigned int w0a, w1a, w0b, w1b;
                asm("v_cvt_pk_bf16_f32 %0, %1, %2"
                    : "=v"(w0a) : "v"(sc[2 * c][mt][0]), "v"(sc[2 * c][mt][1]));
                asm("v_cvt_pk_bf16_f32 %0, %1, %2"
                    : "=v"(w1a) : "v"(sc[2 * c][mt][2]), "v"(sc[2 * c][mt][3]));
                asm("v_cvt_pk_bf16_f32 %0, %1, %2"
                    : "=v"(w0b) : "v"(sc[2 * c + 1][mt][0]), "v"(sc[2 * c + 1][mt][1]));
                asm("v_cvt_pk_bf16_f32 %0, %1, %2"
                    : "=v"(w1b) : "v"(sc[2 * c + 1][mt][2]), "v"(sc[2 * c + 1][mt][3]));
                int idxA = (((quad & 1) << 5) + l15) << 2;   // src lane 2(q&1)*16+l15
                int idxB = idxA + 64;                        // +16 lanes
                int a0 = __builtin_amdgcn_ds_bpermute(idxA, (int)w0a);
                int a1 = __builtin_amdgcn_ds_bpermute(idxA, (int)w1a);
                int a2 = __builtin_amdgcn_ds_bpermute(idxB, (int)w0a);
                int a3 = __builtin_amdgcn_ds_bpermute(idxB, (int)w1a);
                int b0 = __builtin_amdgcn_ds_bpermute(idxA, (int)w0b);
                int b1 = __builtin_amdgcn_ds_bpermute(idxA, (int)w1b);
                int b2 = __builtin_amdgcn_ds_bpermute(idxB, (int)w0b);
                int b3 = __builtin_amdgcn_ds_bpermute(idxB, (int)w1b);
                bool hi = quad >= 2;                          // kt half select
                bpv[mt][0] = (unsigned int)(hi ? b0 : a0);    // keys 8q+0,1
                bpv[mt][1] = (unsigned int)(hi ? b1 : a1);    // keys 8q+2,3
                bpv[mt][2] = (unsigned int)(hi ? b2 : a2);    // keys 8q+4,5
                bpv[mt][3] = (unsigned int)(hi ? b3 : a3);    // keys 8q+6,7
            }
#pragma unroll
            for (int dt = 0; dt < 4; ++dt) {
                bf16x8 ap = *(const bf16x8*)(lV + (dt * 16 + l15) * VSTR + c * 64 + quad * 16);
#pragma unroll
                for (int mt = 0; mt < 2; ++mt) {
                    bf16x8 bp8 = *(bf16x8*)&bpv[mt];
                    ot[dt][mt] = __builtin_amdgcn_mfma_f32_16x16x32_bf16(ap, bp8, ot[dt][mt], 0, 0, 0);
                }
            }
        }
        __builtin_amdgcn_s_setprio(0);
    }

    // epilogue: O^T -> O via padded LDS, coalesced 16B writes
    __syncthreads();
#pragma unroll
    for (int mt = 0; mt < 2; ++mt) {
        float inv_l = 1.0f / l_i[mt];
#pragma unroll
        for (int dt = 0; dt < 4; ++dt) {
            bf16x4 t4;
#pragma unroll
            for (int r = 0; r < 4; ++r) t4[r] = (bf16_t)(ot[dt][mt][r] * inv_l);
            *(bf16x4*)(lK + (wid * 32 + mt * 16 + l15) * KSTR + dt * 32 + quad * 8) = t4;
        }
    }
    __syncthreads();
    {
        char* gout = (char*)(Ctx + ((size_t)b * S_ + q0) * D_ + h * DK_);
#pragma unroll
        for (int j = 0; j < 4; ++j) {
            int flat = j * 4096 + tid * 16;
            bf16x8 v = *(const bf16x8*)(lK + (flat >> 7) * KSTR + (flat & 127));
            *(bf16x8*)(gout + (size_t)(flat >> 7) * (D_ * 2) + (flat & 127)) = v;
        }
    }
}

// ---------------------------------------------------------------------------
// Output GEMM with global_load_lds staging (unchanged, verified).
// ---------------------------------------------------------------------------
__global__ __launch_bounds__(256) void gemm_out(const bf16_t* __restrict__ A,
                                                const bf16_t* __restrict__ Bt,
                                                const float* __restrict__ bias,
                                                float* __restrict__ C) {
    __shared__ alignas(16) bf16_t lA[128 * 64];
    __shared__ alignas(16) bf16_t lB[128 * 64];
    int tid = threadIdx.x;
    int lane = tid & 63, wid = tid >> 6;
    int quad = lane >> 4, l15 = lane & 15;
    int bm = blockIdx.x * 128;
    int bn = blockIdx.y * 128;
    int wm = (wid >> 1) * 64, wn = (wid & 1) * 64;
    f32x4 acc[4][4] = {};

    for (int k0 = 0; k0 < D_; k0 += 64) {
        __syncthreads();
        const char* gA = (const char*)(A + (size_t)bm * D_ + k0);
        const char* gB = (const char*)(Bt + (size_t)bn * D_ + k0);
#pragma unroll
        for (int j = 0; j < 4; ++j) {
            int woff = j * 4096 + wid * 1024;
            int fl = woff + lane * 16;
            int row = fl >> 7, col = fl & 127;
            __builtin_amdgcn_global_load_lds(GLOBAL_AS(gA + (size_t)row * (D_ * 2) + col),
                                             LDS_AS((char*)lA + woff), 16, 0, 0);
            __builtin_amdgcn_global_load_lds(GLOBAL_AS(gB + (size_t)row * (D_ * 2) + col),
                                             LDS_AS((char*)lB + woff), 16, 0, 0);
        }
        __syncthreads();
#pragma unroll
        for (int ks = 0; ks < 2; ++ks) {
            bf16x8 af[4], bfr[4];
#pragma unroll
            for (int i = 0; i < 4; ++i) {
                af[i] = *(const bf16x8*)((const char*)lA + (wm + i * 16 + l15) * 128 + ks * 64 + quad * 16);
                bfr[i] = *(const bf16x8*)((const char*)lB + (wn + i * 16 + l15) * 128 + ks * 64 + quad * 16);
            }
#pragma unroll
            for (int i = 0; i < 4; ++i)
#pragma unroll
                for (int j = 0; j < 4; ++j)
                    acc[i][j] = __builtin_amdgcn_mfma_f32_16x16x32_bf16(af[i], bfr[j], acc[i][j], 0, 0, 0);
        }
    }
#pragma unroll
    for (int i = 0; i < 4; ++i)
#pragma unroll
        for (int j = 0; j < 4; ++j) {
            int r0 = bm + wm + i * 16 + quad * 4;
            int c = bn + wn + j * 16 + l15;
            float bv_ = bias[c];
#pragma unroll
            for (int reg = 0; reg < 4; ++reg)
                C[(size_t)(r0 + reg) * D_ + c] = acc[i][j][reg] + bv_;
        }
}

// ---------------------------------------------------------------------------
// Workspace (41 MB): layout unchanged.
// ---------------------------------------------------------------------------
extern "C" void kernel_launch(void* const* d_in, const int* in_sizes, int n_in,
                              void* d_out, int out_size, void* d_ws, size_t ws_size,
                              hipStream_t stream) {
    const float* query  = (const float*)d_in[0];
    const float* key_in = (const float*)d_in[1];
    const float* value  = (const float*)d_in[2];
    const float* phys   = (const float*)d_in[3];
    const float* Wq     = (const float*)d_in[4];
    const float* bq     = (const float*)d_in[5];
    const float* Wk     = (const float*)d_in[6];
    const float* bk     = (const float*)d_in[7];
    const float* Wv     = (const float*)d_in[8];
    const float* bv     = (const float*)d_in[9];
    const float* Wo     = (const float*)d_in[10];
    const float* bo     = (const float*)d_in[11];
    const float* Pw     = (const float*)d_in[12];
    const float* pb     = (const float*)d_in[13];

    char* ws = (char*)d_ws;
    const size_t MB = 1ull << 20;
    bf16_t* Kb  = (bf16_t*)(ws + 0 * MB);
    bf16_t* QC  = (bf16_t*)(ws + 8 * MB);
    bf16_t* Kin = (bf16_t*)(ws + 16 * MB);
    bf16_t* Vin = (bf16_t*)(ws + 24 * MB);
    bf16_t* WqT = (bf16_t*)(ws + 32 * MB);
    bf16_t* WkT = (bf16_t*)(ws + 34 * MB);
    bf16_t* WvT = (bf16_t*)(ws + 36 * MB);
    bf16_t* WoT = (bf16_t*)(ws + 38 * MB);
    float*  PP  = (float*)(ws + 40 * MB);
    bf16_t* Vt  = (bf16_t*)d_out;                    // lo 8 MB
    bf16_t* Qin = (bf16_t*)((char*)d_out + 8 * MB);  // hi 8 MB

    WPtrs wp;
    wp.w[0] = Wq; wp.w[1] = Wk; wp.w[2] = Wv; wp.w[3] = Wo;
    wp.o[0] = WqT; wp.o[1] = WkT; wp.o[2] = WvT; wp.o[3] = WoT;

    prep<<<11264, 256, 0, stream>>>(query, key_in, value, Qin, Kin, Vin,
                                    wp, phys, Pw, PP);

    dim3 gq(32, 8, 3);
    qkv_gemm<<<gq, 256, 0, stream>>>(Qin, Kin, Vin, WqT, WkT, WvT,
                                     bq, bk, bv, QC, Kb, Vt, PP, pb);

    dim3 fg(S_ / 128, H_, B_);
    flash_attn<<<fg, 256, 0, stream>>>(QC, Kb, Vt, QC);

    dim3 gg(32, 8);
    gemm_out<<<gg, 256, 0, stream>>>(QC, WoT, bo, (float*)d_out);
}

// Round 9
// 249.799 us; speedup vs baseline: 1.0421x; 1.0137x over previous
//
#include <hip/hip_runtime.h>
#include <hip/hip_bf16.h>
#include <stdint.h>
#include <math.h>

typedef __bf16 bf16_t;
typedef __attribute__((ext_vector_type(8))) __bf16 bf16x8;
typedef __attribute__((ext_vector_type(4))) __bf16 bf16x4;
typedef __attribute__((ext_vector_type(4))) short short4_t;
typedef __attribute__((ext_vector_type(4))) float f32x4;

#define GLOBAL_AS(p) ((const __attribute__((address_space(1))) void*)(p))
#define LDS_AS(p)    ((__attribute__((address_space(3))) void*)(p))

// Problem constants
#define B_ 2
#define S_ 2048
#define D_ 1024
#define H_ 16
#define DK_ 64
#define SP_ 128

// Q pre-scale: (1/sqrt(64)) * log2(e) -> scores emerge in log2 units, so
// softmax is ONE v_exp_f32 per element.
#define QSCALE 0.1803368801111144f

static __device__ inline float fast_exp2(float x) {
#if __has_builtin(__builtin_amdgcn_exp2f)
    return __builtin_amdgcn_exp2f(x);
#else
    return __expf(x * 0.6931471805599453f);
#endif
}

// 16x16x16 bf16 MFMA (K=16): A/B = 2 VGPRs (4 bf16), C/D = 4 f32.
// NOTE (r8 lesson): PV stays on K=16 — its B-fragment layout exactly matches
// the transposed-QK C-layout (zero shuffle). K=32 PV needs a cross-quad
// repack whose ds_bpermute cost (+8us, LDS pipe) exceeds the ~6us of
// matrix-pipe time saved. Measured r8: MFMA-busy 20.5->14.1us, total 62->70.
static __device__ inline f32x4 mfma16x16x16bf16(short4_t a, short4_t b, f32x4 c) {
#if __has_builtin(__builtin_amdgcn_mfma_f32_16x16x16bf16_1k)
    return __builtin_amdgcn_mfma_f32_16x16x16bf16_1k(a, b, c, 0, 0, 0);
#else
    asm volatile("v_mfma_f32_16x16x16_bf16 %0, %1, %2, %0" : "+v"(c) : "v"(a), "v"(b));
    return c;
#endif
}

struct WPtrs { const float* w[4]; bf16_t* o[4]; };

// ---------------------------------------------------------------------------
// prep: three independent jobs in one dispatch (unchanged, verified).
// ---------------------------------------------------------------------------
__global__ __launch_bounds__(256) void prep(
    const float* __restrict__ q, const float* __restrict__ k,
    const float* __restrict__ v,
    bf16_t* __restrict__ qo, bf16_t* __restrict__ ko, bf16_t* __restrict__ vo,
    WPtrs wp, const float* __restrict__ phys, const float* __restrict__ Pw,
    float* __restrict__ PP) {
    int bx = blockIdx.x, tid = threadIdx.x;
    if (bx < 6144) {
        int z = bx >> 11, blk = bx & 2047;
        const float* in = (z == 0) ? q : (z == 1) ? k : v;
        bf16_t* out = (z == 0) ? qo : (z == 1) ? ko : vo;
        size_t i = ((size_t)blk * 256 + tid) * 8;
        f32x4 a = *(const f32x4*)(in + i);
        f32x4 b = *(const f32x4*)(in + i + 4);
        bf16x8 o;
#pragma unroll
        for (int e = 0; e < 4; ++e) { o[e] = (bf16_t)a[e]; o[4 + e] = (bf16_t)b[e]; }
        *(bf16x8*)(out + i) = o;
    } else if (bx < 10240) {
        __shared__ bf16_t t[32][33];
        int idx = bx - 6144;
        int z = idx >> 10;
        const float* W = wp.w[z];
        bf16_t* Wt = wp.o[z];
        int gx = (idx & 31) * 32, gy = ((idx >> 5) & 31) * 32;
        int x = tid & 31, y0 = tid >> 5;   // 32 x 8
#pragma unroll
        for (int j = 0; j < 32; j += 8)
            t[y0 + j][x] = (bf16_t)W[(size_t)(gy + y0 + j) * D_ + gx + x];
        __syncthreads();
#pragma unroll
        for (int j = 0; j < 32; j += 8)
            Wt[(size_t)(gx + y0 + j) * D_ + gy + x] = t[x][y0 + j];
    } else {
        int i = (bx - 10240) * 256 + tid;   // B*SP*D = 262144
        int n = i & (D_ - 1);
        int sb = i >> 10;
        float acc = 0.f;
#pragma unroll
        for (int p = 0; p < 3; ++p)
            acc += phys[sb * 3 + p] * Pw[p * D_ + n];
        PP[i] = acc;
    }
}

// ---------------------------------------------------------------------------
// Fused QKV projection GEMM (round-4 version: coalesced LDS-staged epilogue).
// grid (32, 8, 3), block 256. z=0: Q (scaled), z=1: K (+physics), z=2: V^T.
// ---------------------------------------------------------------------------
#define TSTR 272   // epilogue LDS tile row stride (256 data + 16 pad)

__global__ __launch_bounds__(256) void qkv_gemm(
    const bf16_t* __restrict__ Qi, const bf16_t* __restrict__ Ki,
    const bf16_t* __restrict__ Vi,
    const bf16_t* __restrict__ WqT, const bf16_t* __restrict__ WkT,
    const bf16_t* __restrict__ WvT,
    const float* __restrict__ bq, const float* __restrict__ bk,
    const float* __restrict__ bv,
    bf16_t* __restrict__ Qo, bf16_t* __restrict__ Ko, bf16_t* __restrict__ Vo,
    const float* __restrict__ PP, const float* __restrict__ pbp) {
    __shared__ alignas(16) char smem[40960];   // [0,16K) lA, [16K,32K) lB; epilogue tile [0,34816)
    bf16_t* lA = (bf16_t*)smem;
    bf16_t* lB = (bf16_t*)(smem + 16384);
    int z = blockIdx.z;
    const bf16_t* A = (z == 0) ? Qi : (z == 1) ? Ki : Vi;
    const bf16_t* Bt = (z == 0) ? WqT : (z == 1) ? WkT : WvT;
    const float* bias = (z == 0) ? bq : (z == 1) ? bk : bv;

    int tid = threadIdx.x;
    int lane = tid & 63, wid = tid >> 6;
    int quad = lane >> 4, l15 = lane & 15;
    int bm = blockIdx.x * 128;
    int bn = blockIdx.y * 128;
    int wm = (wid >> 1) * 64, wn = (wid & 1) * 64;
    f32x4 acc[4][4] = {};

    for (int k0 = 0; k0 < D_; k0 += 64) {
        __syncthreads();
        const char* gA = (const char*)(A + (size_t)bm * D_ + k0);
        const char* gB = (const char*)(Bt + (size_t)bn * D_ + k0);
#pragma unroll
        for (int j = 0; j < 4; ++j) {
            int woff = j * 4096 + wid * 1024;
            int fl = woff + lane * 16;
            int row = fl >> 7, col = fl & 127;
            __builtin_amdgcn_global_load_lds(GLOBAL_AS(gA + (size_t)row * (D_ * 2) + col),
                                             LDS_AS((char*)lA + woff), 16, 0, 0);
            __builtin_amdgcn_global_load_lds(GLOBAL_AS(gB + (size_t)row * (D_ * 2) + col),
                                             LDS_AS((char*)lB + woff), 16, 0, 0);
        }
        __syncthreads();
#pragma unroll
        for (int ks = 0; ks < 2; ++ks) {
            bf16x8 af[4], bfr[4];
#pragma unroll
            for (int i = 0; i < 4; ++i) {
                af[i] = *(const bf16x8*)((const char*)lA + (wm + i * 16 + l15) * 128 + ks * 64 + quad * 16);
                bfr[i] = *(const bf16x8*)((const char*)lB + (wn + i * 16 + l15) * 128 + ks * 64 + quad * 16);
            }
#pragma unroll
            for (int i = 0; i < 4; ++i)
#pragma unroll
                for (int j = 0; j < 4; ++j)
                    acc[i][j] = __builtin_amdgcn_mfma_f32_16x16x32_bf16(af[i], bfr[j], acc[i][j], 0, 0, 0);
        }
    }

    // ---- epilogue: bias/scale/physics in regs -> LDS tile -> coalesced stores
    __syncthreads();                           // all lA/lB reads retired
    float pb0 = (z == 1) ? pbp[0] : 0.f;
    char* T = smem;
#pragma unroll
    for (int i = 0; i < 4; ++i)
#pragma unroll
        for (int j = 0; j < 4; ++j) {
            int rl0 = wm + i * 16 + quad * 4;      // local row (m / s-dir)
            int c = wn + j * 16 + l15;             // local col (n-dir)
            float bv_ = bias[bn + c];
            if (z == 2) {
                // transpose in LDS: T[c][r] so global store is contiguous in s
                bf16x4 t4;
#pragma unroll
                for (int reg = 0; reg < 4; ++reg) t4[reg] = (bf16_t)(acc[i][j][reg] + bv_);
                *(bf16x4*)(T + c * TSTR + rl0 * 2) = t4;
            } else if (z == 1) {
#pragma unroll
                for (int reg = 0; reg < 4; ++reg) {
                    int r = bm + rl0 + reg;
                    int b = r >> 11, s = r & (S_ - 1);
                    float v = acc[i][j][reg] + bv_ +
                              pb0 * PP[((size_t)(b * SP_ + (s >> 4)) << 10) + ((s & 15) << 6) + ((bn + c) & 63)];
                    *(bf16_t*)(T + (rl0 + reg) * TSTR + c * 2) = (bf16_t)v;
                }
            } else {
#pragma unroll
                for (int reg = 0; reg < 4; ++reg)
                    *(bf16_t*)(T + (rl0 + reg) * TSTR + c * 2) = (bf16_t)((acc[i][j][reg] + bv_) * QSCALE);
            }
        }
    __syncthreads();
    if (z == 2) {
        int b = bm >> 11, s0 = bm & (S_ - 1);
        char* gout = (char*)Vo + (((size_t)(b << 10) + bn) * S_ + s0) * 2;
#pragma unroll
        for (int it = 0; it < 8; ++it) {
            int chunk = it * 256 + tid;
            int row = chunk >> 4, c16 = chunk & 15;   // row = local n
            bf16x8 v = *(const bf16x8*)(T + row * TSTR + c16 * 16);
            *(bf16x8*)(gout + (size_t)row * (S_ * 2) + c16 * 16) = v;
        }
    } else {
        bf16_t* O = (z == 0) ? Qo : Ko;
        char* gout = (char*)(O + (size_t)bm * D_ + bn);
#pragma unroll
        for (int it = 0; it < 8; ++it) {
            int chunk = it * 256 + tid;
            int row = chunk >> 4, c16 = chunk & 15;   // row = local m
            bf16x8 v = *(const bf16x8*)(T + row * TSTR + c16 * 16);
            *(bf16x8*)(gout + (size_t)row * (D_ * 2) + c16 * 16) = v;
        }
    }
}

// ---------------------------------------------------------------------------
// Flash attention — REVERTED to the measured-62.0us form (rounds 0-4 profile):
// 4 waves x 32 q, reg staging, padded LDS, 3D grid, K=16 shuffle-free PV.
// Five structural variants (swizzle+gload_lds, 2x TLP, KVBLK=256, PV-K32,
// XCD decode) all measured >= this; keep the empirical optimum.
// ---------------------------------------------------------------------------
#define KSTR 144   // lK row stride bytes (128 data + 16 pad)
#define VSTR 272   // lV row stride bytes (256 data + 16 pad)

__global__ __launch_bounds__(256) void flash_attn(const bf16_t* Qb,
                                                  const bf16_t* __restrict__ Kb,
                                                  const bf16_t* __restrict__ Vt,
                                                  bf16_t* Ctx) {
    __shared__ alignas(16) char lK[128 * KSTR];   // [key][dk] / Q staging / lO
    __shared__ alignas(16) char lV[64 * VSTR];    // [d][key]
    int tid = threadIdx.x, lane = tid & 63, wid = tid >> 6;
    int quad = lane >> 4, l15 = lane & 15;
    int q0 = blockIdx.x * 128;
    int h = blockIdx.y, b = blockIdx.z;
    const bf16_t* Qh = Qb + ((size_t)b * S_) * D_ + h * DK_;
    const bf16_t* Kh = Kb + ((size_t)b * S_) * D_ + h * DK_;
    const bf16_t* Vh = Vt + ((size_t)b * D_ + h * DK_) * S_;

    {
        const char* g = (const char*)(Qh + (size_t)q0 * D_);
#pragma unroll
        for (int j = 0; j < 4; ++j) {
            int flat = j * 4096 + tid * 16;
            bf16x8 v = *(const bf16x8*)(g + (size_t)(flat >> 7) * (D_ * 2) + (flat & 127));
            *(bf16x8*)(lK + (flat >> 7) * KSTR + (flat & 127)) = v;
        }
    }
    __syncthreads();
    bf16x8 qf[2][2];   // [mt][ks]: B[n=q=l15][dk=ks*32+quad*8+j]
#pragma unroll
    for (int mt = 0; mt < 2; ++mt)
#pragma unroll
        for (int ks = 0; ks < 2; ++ks)
            qf[mt][ks] = *(const bf16x8*)(lK + (wid * 32 + mt * 16 + l15) * KSTR + ks * 64 + quad * 16);

    f32x4 ot[4][2] = {};            // O^T[d-tile][q-tile]
    float l_i[2] = {0.f, 0.f};

    for (int t = 0; t < S_ / 128; ++t) {
        const char* gK = (const char*)(Kh + (size_t)t * 128 * D_);
        const char* gV = (const char*)(Vh + (size_t)t * 128);
        bf16x8 vk[4], vv[4];
#pragma unroll
        for (int j = 0; j < 4; ++j) {
            int flat = j * 4096 + tid * 16;
            vk[j] = *(const bf16x8*)(gK + (size_t)(flat >> 7) * (D_ * 2) + (flat & 127));
            vv[j] = *(const bf16x8*)(gV + (size_t)(flat >> 8) * (S_ * 2) + (flat & 255));
        }
        __syncthreads();
#pragma unroll
        for (int j = 0; j < 4; ++j) {
            int flat = j * 4096 + tid * 16;
            *(bf16x8*)(lK + (flat >> 7) * KSTR + (flat & 127)) = vk[j];
            *(bf16x8*)(lV + (flat >> 8) * VSTR + (flat & 255)) = vv[j];
        }
        __syncthreads();

        // St = K·Q^T  (log2-domain scores)
        f32x4 sc[8][2];
#pragma unroll
        for (int kt = 0; kt < 8; ++kt)
#pragma unroll
            for (int mt = 0; mt < 2; ++mt) sc[kt][mt] = (f32x4){0.f, 0.f, 0.f, 0.f};
#pragma unroll
        for (int kt = 0; kt < 8; ++kt) {
            bf16x8 kf0 = *(const bf16x8*)(lK + (kt * 16 + l15) * KSTR + quad * 16);
            bf16x8 kf1 = *(const bf16x8*)(lK + (kt * 16 + l15) * KSTR + 64 + quad * 16);
#pragma unroll
            for (int mt = 0; mt < 2; ++mt) {
                sc[kt][mt] = __builtin_amdgcn_mfma_f32_16x16x32_bf16(kf0, qf[mt][0], sc[kt][mt], 0, 0, 0);
                sc[kt][mt] = __builtin_amdgcn_mfma_f32_16x16x32_bf16(kf1, qf[mt][1], sc[kt][mt], 0, 0, 0);
            }
        }

        // softmax numerator: p = 2^s (one v_exp_f32 each); accumulate l
#pragma unroll
        for (int mt = 0; mt < 2; ++mt) {
            float rsum = 0.f;
#pragma unroll
            for (int kt = 0; kt < 8; ++kt)
#pragma unroll
                for (int r = 0; r < 4; ++r) {
                    float p = fast_exp2(sc[kt][mt][r]);
                    sc[kt][mt][r] = p;
                    rsum += p;
                }
            rsum += __shfl_xor(rsum, 16, 64);
            rsum += __shfl_xor(rsum, 32, 64);
            l_i[mt] += rsum;
        }

        // PV: O^T += V^T·P^T, 16x16x16, P direct from registers
#pragma unroll
        for (int kt = 0; kt < 8; ++kt) {
            short4_t bp[2];
#pragma unroll
            for (int mt = 0; mt < 2; ++mt) {
                bf16x4 t4;
#pragma unroll
                for (int r = 0; r < 4; ++r) t4[r] = (bf16_t)sc[kt][mt][r];
                bp[mt] = *(short4_t*)&t4;
            }
#pragma unroll
            for (int dt = 0; dt < 4; ++dt) {
                bf16x4 a4 = *(const bf16x4*)(lV + (dt * 16 + l15) * VSTR + kt * 32 + quad * 8);
                short4_t ap = *(short4_t*)&a4;
#pragma unroll
                for (int mt = 0; mt < 2; ++mt)
                    ot[dt][mt] = mfma16x16x16bf16(ap, bp[mt], ot[dt][mt]);
            }
        }
    }

    // epilogue: O^T -> O via padded LDS, coalesced 16B writes
    __syncthreads();
#pragma unroll
    for (int mt = 0; mt < 2; ++mt) {
        float inv_l = 1.0f / l_i[mt];
#pragma unroll
        for (int dt = 0; dt < 4; ++dt) {
            bf16x4 t4;
#pragma unroll
            for (int r = 0; r < 4; ++r) t4[r] = (bf16_t)(ot[dt][mt][r] * inv_l);
            *(bf16x4*)(lK + (wid * 32 + mt * 16 + l15) * KSTR + dt * 32 + quad * 8) = t4;
        }
    }
    __syncthreads();
    {
        char* gout = (char*)(Ctx + ((size_t)b * S_ + q0) * D_ + h * DK_);
#pragma unroll
        for (int j = 0; j < 4; ++j) {
            int flat = j * 4096 + tid * 16;
            bf16x8 v = *(const bf16x8*)(lK + (flat >> 7) * KSTR + (flat & 127));
            *(bf16x8*)(gout + (size_t)(flat >> 7) * (D_ * 2) + (flat & 127)) = v;
        }
    }
}

// ---------------------------------------------------------------------------
// Output GEMM — NEW: r4-proven coalesced LDS-staged epilogue (fp32, two
// 64-row passes through a 528B-stride tile; 16 vector stores/thread replace
// 64 scalar stores with 4-row striping). Main loop unchanged.
// ---------------------------------------------------------------------------
#define TSTR4 528   // f32 epilogue row stride (512 data + 16 pad)

__global__ __launch_bounds__(256) void gemm_out(const bf16_t* __restrict__ A,
                                                const bf16_t* __restrict__ Bt,
                                                const float* __restrict__ bias,
                                                float* __restrict__ C) {
    __shared__ alignas(16) char smem[40960];   // lA 16K | lB 16K; epilogue T 33.8K
    bf16_t* lA = (bf16_t*)smem;
    bf16_t* lB = (bf16_t*)(smem + 16384);
    int tid = threadIdx.x;
    int lane = tid & 63, wid = tid >> 6;
    int quad = lane >> 4, l15 = lane & 15;
    int bm = blockIdx.x * 128;
    int bn = blockIdx.y * 128;
    int wm = (wid >> 1) * 64, wn = (wid & 1) * 64;
    f32x4 acc[4][4] = {};

    for (int k0 = 0; k0 < D_; k0 += 64) {
        __syncthreads();
        const char* gA = (const char*)(A + (size_t)bm * D_ + k0);
        const char* gB = (const char*)(Bt + (size_t)bn * D_ + k0);
#pragma unroll
        for (int j = 0; j < 4; ++j) {
            int woff = j * 4096 + wid * 1024;
            int fl = woff + lane * 16;
            int row = fl >> 7, col = fl & 127;
            __builtin_amdgcn_global_load_lds(GLOBAL_AS(gA + (size_t)row * (D_ * 2) + col),
                                             LDS_AS((char*)lA + woff), 16, 0, 0);
            __builtin_amdgcn_global_load_lds(GLOBAL_AS(gB + (size_t)row * (D_ * 2) + col),
                                             LDS_AS((char*)lB + woff), 16, 0, 0);
        }
        __syncthreads();
#pragma unroll
        for (int ks = 0; ks < 2; ++ks) {
            bf16x8 af[4], bfr[4];
#pragma unroll
            for (int i = 0; i < 4; ++i) {
                af[i] = *(const bf16x8*)((const char*)lA + (wm + i * 16 + l15) * 128 + ks * 64 + quad * 16);
                bfr[i] = *(const bf16x8*)((const char*)lB + (wn + i * 16 + l15) * 128 + ks * 64 + quad * 16);
            }
#pragma unroll
            for (int i = 0; i < 4; ++i)
#pragma unroll
                for (int j = 0; j < 4; ++j)
                    acc[i][j] = __builtin_amdgcn_mfma_f32_16x16x32_bf16(af[i], bfr[j], acc[i][j], 0, 0, 0);
        }
    }

    // ---- epilogue: two 64-row passes, LDS-staged, coalesced f32x4 stores
    __syncthreads();                           // all lA/lB reads retired
    char* T = smem;
#pragma unroll
    for (int p = 0; p < 2; ++p) {
        if ((wid >> 1) == p) {                 // waves owning this row-half
#pragma unroll
            for (int i = 0; i < 4; ++i)
#pragma unroll
                for (int j = 0; j < 4; ++j) {
                    int rl0 = i * 16 + quad * 4;       // row within half [0,64)
                    int c = wn + j * 16 + l15;         // col [0,128)
                    float bv_ = bias[bn + c];
#pragma unroll
                    for (int reg = 0; reg < 4; ++reg)
                        *(float*)(T + (rl0 + reg) * TSTR4 + c * 4) = acc[i][j][reg] + bv_;
                }
        }
        __syncthreads();
        {
            char* gout = (char*)(C + (size_t)(bm + p * 64) * D_ + bn);
#pragma unroll
            for (int it = 0; it < 8; ++it) {
                int chunk = it * 256 + tid;
                int row = chunk >> 5, c16 = chunk & 31;   // 32 x 16B per row
                f32x4 v = *(const f32x4*)(T + row * TSTR4 + c16 * 16);
                *(f32x4*)(gout + (size_t)row * (D_ * 4) + c16 * 16) = v;
            }
        }
        __syncthreads();
    }
}

// ---------------------------------------------------------------------------
// Workspace (41 MB): layout unchanged.
// ---------------------------------------------------------------------------
extern "C" void kernel_launch(void* const* d_in, const int* in_sizes, int n_in,
                              void* d_out, int out_size, void* d_ws, size_t ws_size,
                              hipStream_t stream) {
    const float* query  = (const float*)d_in[0];
    const float* key_in = (const float*)d_in[1];
    const float* value  = (const float*)d_in[2];
    const float* phys   = (const float*)d_in[3];
    const float* Wq     = (const float*)d_in[4];
    const float* bq     = (const float*)d_in[5];
    const float* Wk     = (const float*)d_in[6];
    const float* bk     = (const float*)d_in[7];
    const float* Wv     = (const float*)d_in[8];
    const float* bv     = (const float*)d_in[9];
    const float* Wo     = (const float*)d_in[10];
    const float* bo     = (const float*)d_in[11];
    const float* Pw     = (const float*)d_in[12];
    const float* pb     = (const float*)d_in[13];

    char* ws = (char*)d_ws;
    const size_t MB = 1ull << 20;
    bf16_t* Kb  = (bf16_t*)(ws + 0 * MB);
    bf16_t* QC  = (bf16_t*)(ws + 8 * MB);
    bf16_t* Kin = (bf16_t*)(ws + 16 * MB);
    bf16_t* Vin = (bf16_t*)(ws + 24 * MB);
    bf16_t* WqT = (bf16_t*)(ws + 32 * MB);
    bf16_t* WkT = (bf16_t*)(ws + 34 * MB);
    bf16_t* WvT = (bf16_t*)(ws + 36 * MB);
    bf16_t* WoT = (bf16_t*)(ws + 38 * MB);
    float*  PP  = (float*)(ws + 40 * MB);
    bf16_t* Vt  = (bf16_t*)d_out;                    // lo 8 MB
    bf16_t* Qin = (bf16_t*)((char*)d_out + 8 * MB);  // hi 8 MB

    WPtrs wp;
    wp.w[0] = Wq; wp.w[1] = Wk; wp.w[2] = Wv; wp.w[3] = Wo;
    wp.o[0] = WqT; wp.o[1] = WkT; wp.o[2] = WvT; wp.o[3] = WoT;

    prep<<<11264, 256, 0, stream>>>(query, key_in, value, Qin, Kin, Vin,
                                    wp, phys, Pw, PP);

    dim3 gq(32, 8, 3);
    qkv_gemm<<<gq, 256, 0, stream>>>(Qin, Kin, Vin, WqT, WkT, WvT,
                                     bq, bk, bv, QC, Kb, Vt, PP, pb);

    dim3 fg(S_ / 128, H_, B_);
    flash_attn<<<fg, 256, 0, stream>>>(QC, Kb, Vt, QC);

    dim3 gg(32, 8);
    gemm_out<<<gg, 256, 0, stream>>>(QC, WoT, bo, (float*)d_out);
}

// Round 10
// 247.549 us; speedup vs baseline: 1.0515x; 1.0091x over previous
//
#include <hip/hip_runtime.h>
#include <hip/hip_bf16.h>
#include <stdint.h>
#include <math.h>

typedef __bf16 bf16_t;
typedef __attribute__((ext_vector_type(8))) __bf16 bf16x8;
typedef __attribute__((ext_vector_type(4))) __bf16 bf16x4;
typedef __attribute__((ext_vector_type(4))) short short4_t;
typedef __attribute__((ext_vector_type(4))) float f32x4;

#define GLOBAL_AS(p) ((const __attribute__((address_space(1))) void*)(p))
#define LDS_AS(p)    ((__attribute__((address_space(3))) void*)(p))

// Problem constants
#define B_ 2
#define S_ 2048
#define D_ 1024
#define H_ 16
#define DK_ 64
#define SP_ 128

// Q pre-scale: (1/sqrt(64)) * log2(e) -> scores emerge in log2 units, so
// softmax is ONE v_exp_f32 per element.
#define QSCALE 0.1803368801111144f

static __device__ inline float fast_exp2(float x) {
#if __has_builtin(__builtin_amdgcn_exp2f)
    return __builtin_amdgcn_exp2f(x);
#else
    return __expf(x * 0.6931471805599453f);
#endif
}

// 16x16x16 bf16 MFMA (K=16): A/B = 2 VGPRs (4 bf16), C/D = 4 f32.
// NOTE (r8 lesson): PV stays on K=16 — its B-fragment layout exactly matches
// the transposed-QK C-layout (zero shuffle). K=32 PV needs a cross-quad
// repack whose ds_bpermute cost (+8us, LDS pipe) exceeds the ~6us of
// matrix-pipe time saved. Measured r8: MFMA-busy 20.5->14.1us, total 62->70.
static __device__ inline f32x4 mfma16x16x16bf16(short4_t a, short4_t b, f32x4 c) {
#if __has_builtin(__builtin_amdgcn_mfma_f32_16x16x16bf16_1k)
    return __builtin_amdgcn_mfma_f32_16x16x16bf16_1k(a, b, c, 0, 0, 0);
#else
    asm volatile("v_mfma_f32_16x16x16_bf16 %0, %1, %2, %0" : "+v"(c) : "v"(a), "v"(b));
    return c;
#endif
}

struct WPtrs { const float* w[4]; bf16_t* o[4]; };

// ---------------------------------------------------------------------------
// prep: same three jobs, now 2048 blocks with a grid-stride loop (G11: the
// old 11264-tiny-block launch is a scheduling-overhead suspect for the
// unaccounted ~110us in the per-iteration budget).
// ---------------------------------------------------------------------------
__global__ __launch_bounds__(256) void prep(
    const float* __restrict__ q, const float* __restrict__ k,
    const float* __restrict__ v,
    bf16_t* __restrict__ qo, bf16_t* __restrict__ ko, bf16_t* __restrict__ vo,
    WPtrs wp, const float* __restrict__ phys, const float* __restrict__ Pw,
    float* __restrict__ PP) {
    __shared__ bf16_t t[32][33];
    int tid = threadIdx.x;
    for (int bx = blockIdx.x; bx < 11264; bx += 2048) {
        if (bx < 6144) {
            int z = bx >> 11, blk = bx & 2047;
            const float* in = (z == 0) ? q : (z == 1) ? k : v;
            bf16_t* out = (z == 0) ? qo : (z == 1) ? ko : vo;
            size_t i = ((size_t)blk * 256 + tid) * 8;
            f32x4 a = *(const f32x4*)(in + i);
            f32x4 b = *(const f32x4*)(in + i + 4);
            bf16x8 o;
#pragma unroll
            for (int e = 0; e < 4; ++e) { o[e] = (bf16_t)a[e]; o[4 + e] = (bf16_t)b[e]; }
            *(bf16x8*)(out + i) = o;
        } else if (bx < 10240) {
            __syncthreads();   // t[][] safe vs previous iteration's readers
            int idx = bx - 6144;
            int z = idx >> 10;
            const float* W = wp.w[z];
            bf16_t* Wt = wp.o[z];
            int gx = (idx & 31) * 32, gy = ((idx >> 5) & 31) * 32;
            int x = tid & 31, y0 = tid >> 5;   // 32 x 8
#pragma unroll
            for (int j = 0; j < 32; j += 8)
                t[y0 + j][x] = (bf16_t)W[(size_t)(gy + y0 + j) * D_ + gx + x];
            __syncthreads();
#pragma unroll
            for (int j = 0; j < 32; j += 8)
                Wt[(size_t)(gx + y0 + j) * D_ + gy + x] = t[x][y0 + j];
        } else {
            int i = (bx - 10240) * 256 + tid;   // B*SP*D = 262144
            int n = i & (D_ - 1);
            int sb = i >> 10;
            float acc = 0.f;
#pragma unroll
            for (int p = 0; p < 3; ++p)
                acc += phys[sb * 3 + p] * Pw[p * D_ + n];
            PP[i] = acc;
        }
    }
}

// ---------------------------------------------------------------------------
// Fused QKV projection GEMM (round-4 version: coalesced LDS-staged epilogue).
// grid (32, 8, 3), block 256. z=0: Q (scaled), z=1: K (+physics), z=2: V^T.
// UNCHANGED this round.
// ---------------------------------------------------------------------------
#define TSTR 272   // epilogue LDS tile row stride (256 data + 16 pad)

__global__ __launch_bounds__(256) void qkv_gemm(
    const bf16_t* __restrict__ Qi, const bf16_t* __restrict__ Ki,
    const bf16_t* __restrict__ Vi,
    const bf16_t* __restrict__ WqT, const bf16_t* __restrict__ WkT,
    const bf16_t* __restrict__ WvT,
    const float* __restrict__ bq, const float* __restrict__ bk,
    const float* __restrict__ bv,
    bf16_t* __restrict__ Qo, bf16_t* __restrict__ Ko, bf16_t* __restrict__ Vo,
    const float* __restrict__ PP, const float* __restrict__ pbp) {
    __shared__ alignas(16) char smem[40960];   // [0,16K) lA, [16K,32K) lB; epilogue tile [0,34816)
    bf16_t* lA = (bf16_t*)smem;
    bf16_t* lB = (bf16_t*)(smem + 16384);
    int z = blockIdx.z;
    const bf16_t* A = (z == 0) ? Qi : (z == 1) ? Ki : Vi;
    const bf16_t* Bt = (z == 0) ? WqT : (z == 1) ? WkT : WvT;
    const float* bias = (z == 0) ? bq : (z == 1) ? bk : bv;

    int tid = threadIdx.x;
    int lane = tid & 63, wid = tid >> 6;
    int quad = lane >> 4, l15 = lane & 15;
    int bm = blockIdx.x * 128;
    int bn = blockIdx.y * 128;
    int wm = (wid >> 1) * 64, wn = (wid & 1) * 64;
    f32x4 acc[4][4] = {};

    for (int k0 = 0; k0 < D_; k0 += 64) {
        __syncthreads();
        const char* gA = (const char*)(A + (size_t)bm * D_ + k0);
        const char* gB = (const char*)(Bt + (size_t)bn * D_ + k0);
#pragma unroll
        for (int j = 0; j < 4; ++j) {
            int woff = j * 4096 + wid * 1024;
            int fl = woff + lane * 16;
            int row = fl >> 7, col = fl & 127;
            __builtin_amdgcn_global_load_lds(GLOBAL_AS(gA + (size_t)row * (D_ * 2) + col),
                                             LDS_AS((char*)lA + woff), 16, 0, 0);
            __builtin_amdgcn_global_load_lds(GLOBAL_AS(gB + (size_t)row * (D_ * 2) + col),
                                             LDS_AS((char*)lB + woff), 16, 0, 0);
        }
        __syncthreads();
#pragma unroll
        for (int ks = 0; ks < 2; ++ks) {
            bf16x8 af[4], bfr[4];
#pragma unroll
            for (int i = 0; i < 4; ++i) {
                af[i] = *(const bf16x8*)((const char*)lA + (wm + i * 16 + l15) * 128 + ks * 64 + quad * 16);
                bfr[i] = *(const bf16x8*)((const char*)lB + (wn + i * 16 + l15) * 128 + ks * 64 + quad * 16);
            }
#pragma unroll
            for (int i = 0; i < 4; ++i)
#pragma unroll
                for (int j = 0; j < 4; ++j)
                    acc[i][j] = __builtin_amdgcn_mfma_f32_16x16x32_bf16(af[i], bfr[j], acc[i][j], 0, 0, 0);
        }
    }

    // ---- epilogue: bias/scale/physics in regs -> LDS tile -> coalesced stores
    __syncthreads();                           // all lA/lB reads retired
    float pb0 = (z == 1) ? pbp[0] : 0.f;
    char* T = smem;
#pragma unroll
    for (int i = 0; i < 4; ++i)
#pragma unroll
        for (int j = 0; j < 4; ++j) {
            int rl0 = wm + i * 16 + quad * 4;      // local row (m / s-dir)
            int c = wn + j * 16 + l15;             // local col (n-dir)
            float bv_ = bias[bn + c];
            if (z == 2) {
                // transpose in LDS: T[c][r] so global store is contiguous in s
                bf16x4 t4;
#pragma unroll
                for (int reg = 0; reg < 4; ++reg) t4[reg] = (bf16_t)(acc[i][j][reg] + bv_);
                *(bf16x4*)(T + c * TSTR + rl0 * 2) = t4;
            } else if (z == 1) {
#pragma unroll
                for (int reg = 0; reg < 4; ++reg) {
                    int r = bm + rl0 + reg;
                    int b = r >> 11, s = r & (S_ - 1);
                    float v = acc[i][j][reg] + bv_ +
                              pb0 * PP[((size_t)(b * SP_ + (s >> 4)) << 10) + ((s & 15) << 6) + ((bn + c) & 63)];
                    *(bf16_t*)(T + (rl0 + reg) * TSTR + c * 2) = (bf16_t)v;
                }
            } else {
#pragma unroll
                for (int reg = 0; reg < 4; ++reg)
                    *(bf16_t*)(T + (rl0 + reg) * TSTR + c * 2) = (bf16_t)((acc[i][j][reg] + bv_) * QSCALE);
            }
        }
    __syncthreads();
    if (z == 2) {
        int b = bm >> 11, s0 = bm & (S_ - 1);
        char* gout = (char*)Vo + (((size_t)(b << 10) + bn) * S_ + s0) * 2;
#pragma unroll
        for (int it = 0; it < 8; ++it) {
            int chunk = it * 256 + tid;
            int row = chunk >> 4, c16 = chunk & 15;   // row = local n
            bf16x8 v = *(const bf16x8*)(T + row * TSTR + c16 * 16);
            *(bf16x8*)(gout + (size_t)row * (S_ * 2) + c16 * 16) = v;
        }
    } else {
        bf16_t* O = (z == 0) ? Qo : Ko;
        char* gout = (char*)(O + (size_t)bm * D_ + bn);
#pragma unroll
        for (int it = 0; it < 8; ++it) {
            int chunk = it * 256 + tid;
            int row = chunk >> 4, c16 = chunk & 15;   // row = local m
            bf16x8 v = *(const bf16x8*)(T + row * TSTR + c16 * 16);
            *(bf16x8*)(gout + (size_t)row * (D_ * 2) + c16 * 16) = v;
        }
    }
}

// ---------------------------------------------------------------------------
// Flash attention — measured-60.4us form (UNCHANGED): 4 waves x 32 q, reg
// staging, padded LDS, 3D grid, K=16 shuffle-free PV.
// ---------------------------------------------------------------------------
#define KSTR 144   // lK row stride bytes (128 data + 16 pad)
#define VSTR 272   // lV row stride bytes (256 data + 16 pad)

__global__ __launch_bounds__(256) void flash_attn(const bf16_t* Qb,
                                                  const bf16_t* __restrict__ Kb,
                                                  const bf16_t* __restrict__ Vt,
                                                  bf16_t* Ctx) {
    __shared__ alignas(16) char lK[128 * KSTR];   // [key][dk] / Q staging / lO
    __shared__ alignas(16) char lV[64 * VSTR];    // [d][key]
    int tid = threadIdx.x, lane = tid & 63, wid = tid >> 6;
    int quad = lane >> 4, l15 = lane & 15;
    int q0 = blockIdx.x * 128;
    int h = blockIdx.y, b = blockIdx.z;
    const bf16_t* Qh = Qb + ((size_t)b * S_) * D_ + h * DK_;
    const bf16_t* Kh = Kb + ((size_t)b * S_) * D_ + h * DK_;
    const bf16_t* Vh = Vt + ((size_t)b * D_ + h * DK_) * S_;

    {
        const char* g = (const char*)(Qh + (size_t)q0 * D_);
#pragma unroll
        for (int j = 0; j < 4; ++j) {
            int flat = j * 4096 + tid * 16;
            bf16x8 v = *(const bf16x8*)(g + (size_t)(flat >> 7) * (D_ * 2) + (flat & 127));
            *(bf16x8*)(lK + (flat >> 7) * KSTR + (flat & 127)) = v;
        }
    }
    __syncthreads();
    bf16x8 qf[2][2];   // [mt][ks]: B[n=q=l15][dk=ks*32+quad*8+j]
#pragma unroll
    for (int mt = 0; mt < 2; ++mt)
#pragma unroll
        for (int ks = 0; ks < 2; ++ks)
            qf[mt][ks] = *(const bf16x8*)(lK + (wid * 32 + mt * 16 + l15) * KSTR + ks * 64 + quad * 16);

    f32x4 ot[4][2] = {};            // O^T[d-tile][q-tile]
    float l_i[2] = {0.f, 0.f};

    for (int t = 0; t < S_ / 128; ++t) {
        const char* gK = (const char*)(Kh + (size_t)t * 128 * D_);
        const char* gV = (const char*)(Vh + (size_t)t * 128);
        bf16x8 vk[4], vv[4];
#pragma unroll
        for (int j = 0; j < 4; ++j) {
            int flat = j * 4096 + tid * 16;
            vk[j] = *(const bf16x8*)(gK + (size_t)(flat >> 7) * (D_ * 2) + (flat & 127));
            vv[j] = *(const bf16x8*)(gV + (size_t)(flat >> 8) * (S_ * 2) + (flat & 255));
        }
        __syncthreads();
#pragma unroll
        for (int j = 0; j < 4; ++j) {
            int flat = j * 4096 + tid * 16;
            *(bf16x8*)(lK + (flat >> 7) * KSTR + (flat & 127)) = vk[j];
            *(bf16x8*)(lV + (flat >> 8) * VSTR + (flat & 255)) = vv[j];
        }
        __syncthreads();

        // St = K·Q^T  (log2-domain scores)
        f32x4 sc[8][2];
#pragma unroll
        for (int kt = 0; kt < 8; ++kt)
#pragma unroll
            for (int mt = 0; mt < 2; ++mt) sc[kt][mt] = (f32x4){0.f, 0.f, 0.f, 0.f};
#pragma unroll
        for (int kt = 0; kt < 8; ++kt) {
            bf16x8 kf0 = *(const bf16x8*)(lK + (kt * 16 + l15) * KSTR + quad * 16);
            bf16x8 kf1 = *(const bf16x8*)(lK + (kt * 16 + l15) * KSTR + 64 + quad * 16);
#pragma unroll
            for (int mt = 0; mt < 2; ++mt) {
                sc[kt][mt] = __builtin_amdgcn_mfma_f32_16x16x32_bf16(kf0, qf[mt][0], sc[kt][mt], 0, 0, 0);
                sc[kt][mt] = __builtin_amdgcn_mfma_f32_16x16x32_bf16(kf1, qf[mt][1], sc[kt][mt], 0, 0, 0);
            }
        }

        // softmax numerator: p = 2^s (one v_exp_f32 each); accumulate l
#pragma unroll
        for (int mt = 0; mt < 2; ++mt) {
            float rsum = 0.f;
#pragma unroll
            for (int kt = 0; kt < 8; ++kt)
#pragma unroll
                for (int r = 0; r < 4; ++r) {
                    float p = fast_exp2(sc[kt][mt][r]);
                    sc[kt][mt][r] = p;
                    rsum += p;
                }
            rsum += __shfl_xor(rsum, 16, 64);
            rsum += __shfl_xor(rsum, 32, 64);
            l_i[mt] += rsum;
        }

        // PV: O^T += V^T·P^T, 16x16x16, P direct from registers
#pragma unroll
        for (int kt = 0; kt < 8; ++kt) {
            short4_t bp[2];
#pragma unroll
            for (int mt = 0; mt < 2; ++mt) {
                bf16x4 t4;
#pragma unroll
                for (int r = 0; r < 4; ++r) t4[r] = (bf16_t)sc[kt][mt][r];
                bp[mt] = *(short4_t*)&t4;
            }
#pragma unroll
            for (int dt = 0; dt < 4; ++dt) {
                bf16x4 a4 = *(const bf16x4*)(lV + (dt * 16 + l15) * VSTR + kt * 32 + quad * 8);
                short4_t ap = *(short4_t*)&a4;
#pragma unroll
                for (int mt = 0; mt < 2; ++mt)
                    ot[dt][mt] = mfma16x16x16bf16(ap, bp[mt], ot[dt][mt]);
            }
        }
    }

    // epilogue: O^T -> O via padded LDS, coalesced 16B writes
    __syncthreads();
#pragma unroll
    for (int mt = 0; mt < 2; ++mt) {
        float inv_l = 1.0f / l_i[mt];
#pragma unroll
        for (int dt = 0; dt < 4; ++dt) {
            bf16x4 t4;
#pragma unroll
            for (int r = 0; r < 4; ++r) t4[r] = (bf16_t)(ot[dt][mt][r] * inv_l);
            *(bf16x4*)(lK + (wid * 32 + mt * 16 + l15) * KSTR + dt * 32 + quad * 8) = t4;
        }
    }
    __syncthreads();
    {
        char* gout = (char*)(Ctx + ((size_t)b * S_ + q0) * D_ + h * DK_);
#pragma unroll
        for (int j = 0; j < 4; ++j) {
            int flat = j * 4096 + tid * 16;
            bf16x8 v = *(const bf16x8*)(lK + (flat >> 7) * KSTR + (flat & 127));
            *(bf16x8*)(gout + (size_t)(flat >> 7) * (D_ * 2) + (flat & 127)) = v;
        }
    }
}

// ---------------------------------------------------------------------------
// Output GEMM — BM=64 x BN=128 tiles, grid (64,8) = 512 blocks = 2 blocks/CU
// (was 256 = 1/CU: the vmcnt(0)+barrier drain had no cross-block cover).
// B-panel re-reads double but B = 2MB (L2-resident). Direct fp32 epilogue
// (r8->r9 proved the LDS-staged variant is a null for this store pattern).
// ---------------------------------------------------------------------------
__global__ __launch_bounds__(256) void gemm_out(const bf16_t* __restrict__ A,
                                                const bf16_t* __restrict__ Bt,
                                                const float* __restrict__ bias,
                                                float* __restrict__ C) {
    __shared__ alignas(16) bf16_t lA[64 * 64];    // 8KB
    __shared__ alignas(16) bf16_t lB[128 * 64];   // 16KB
    int tid = threadIdx.x;
    int lane = tid & 63, wid = tid >> 6;
    int quad = lane >> 4, l15 = lane & 15;
    int bm = blockIdx.x * 64;
    int bn = blockIdx.y * 128;
    int wm = (wid >> 1) * 32, wn = (wid & 1) * 64;
    f32x4 acc[2][4] = {};

    for (int k0 = 0; k0 < D_; k0 += 64) {
        __syncthreads();
        const char* gA = (const char*)(A + (size_t)bm * D_ + k0);
        const char* gB = (const char*)(Bt + (size_t)bn * D_ + k0);
#pragma unroll
        for (int j = 0; j < 2; ++j) {
            int fl = j * 4096 + tid * 16;
            int row = fl >> 7, col = fl & 127;
            __builtin_amdgcn_global_load_lds(GLOBAL_AS(gA + (size_t)row * (D_ * 2) + col),
                                             LDS_AS((char*)lA + fl), 16, 0, 0);
        }
#pragma unroll
        for (int j = 0; j < 4; ++j) {
            int fl = j * 4096 + tid * 16;
            int row = fl >> 7, col = fl & 127;
            __builtin_amdgcn_global_load_lds(GLOBAL_AS(gB + (size_t)row * (D_ * 2) + col),
                                             LDS_AS((char*)lB + fl), 16, 0, 0);
        }
        __syncthreads();
#pragma unroll
        for (int ks = 0; ks < 2; ++ks) {
            bf16x8 af[2], bfr[4];
#pragma unroll
            for (int i = 0; i < 2; ++i)
                af[i] = *(const bf16x8*)((const char*)lA + (wm + i * 16 + l15) * 128 + ks * 64 + quad * 16);
#pragma unroll
            for (int j = 0; j < 4; ++j)
                bfr[j] = *(const bf16x8*)((const char*)lB + (wn + j * 16 + l15) * 128 + ks * 64 + quad * 16);
#pragma unroll
            for (int i = 0; i < 2; ++i)
#pragma unroll
                for (int j = 0; j < 4; ++j)
                    acc[i][j] = __builtin_amdgcn_mfma_f32_16x16x32_bf16(af[i], bfr[j], acc[i][j], 0, 0, 0);
        }
    }
#pragma unroll
    for (int i = 0; i < 2; ++i)
#pragma unroll
        for (int j = 0; j < 4; ++j) {
            int r0 = bm + wm + i * 16 + quad * 4;
            int c = bn + wn + j * 16 + l15;
            float bv_ = bias[c];
#pragma unroll
            for (int reg = 0; reg < 4; ++reg)
                C[(size_t)(r0 + reg) * D_ + c] = acc[i][j][reg] + bv_;
        }
}

// ---------------------------------------------------------------------------
// Workspace (41 MB): layout unchanged.
// ---------------------------------------------------------------------------
extern "C" void kernel_launch(void* const* d_in, const int* in_sizes, int n_in,
                              void* d_out, int out_size, void* d_ws, size_t ws_size,
                              hipStream_t stream) {
    const float* query  = (const float*)d_in[0];
    const float* key_in = (const float*)d_in[1];
    const float* value  = (const float*)d_in[2];
    const float* phys   = (const float*)d_in[3];
    const float* Wq     = (const float*)d_in[4];
    const float* bq     = (const float*)d_in[5];
    const float* Wk     = (const float*)d_in[6];
    const float* bk     = (const float*)d_in[7];
    const float* Wv     = (const float*)d_in[8];
    const float* bv     = (const float*)d_in[9];
    const float* Wo     = (const float*)d_in[10];
    const float* bo     = (const float*)d_in[11];
    const float* Pw     = (const float*)d_in[12];
    const float* pb     = (const float*)d_in[13];

    char* ws = (char*)d_ws;
    const size_t MB = 1ull << 20;
    bf16_t* Kb  = (bf16_t*)(ws + 0 * MB);
    bf16_t* QC  = (bf16_t*)(ws + 8 * MB);
    bf16_t* Kin = (bf16_t*)(ws + 16 * MB);
    bf16_t* Vin = (bf16_t*)(ws + 24 * MB);
    bf16_t* WqT = (bf16_t*)(ws + 32 * MB);
    bf16_t* WkT = (bf16_t*)(ws + 34 * MB);
    bf16_t* WvT = (bf16_t*)(ws + 36 * MB);
    bf16_t* WoT = (bf16_t*)(ws + 38 * MB);
    float*  PP  = (float*)(ws + 40 * MB);
    bf16_t* Vt  = (bf16_t*)d_out;                    // lo 8 MB
    bf16_t* Qin = (bf16_t*)((char*)d_out + 8 * MB);  // hi 8 MB

    WPtrs wp;
    wp.w[0] = Wq; wp.w[1] = Wk; wp.w[2] = Wv; wp.w[3] = Wo;
    wp.o[0] = WqT; wp.o[1] = WkT; wp.o[2] = WvT; wp.o[3] = WoT;

    prep<<<2048, 256, 0, stream>>>(query, key_in, value, Qin, Kin, Vin,
                                   wp, phys, Pw, PP);

    dim3 gq(32, 8, 3);
    qkv_gemm<<<gq, 256, 0, stream>>>(Qin, Kin, Vin, WqT, WkT, WvT,
                                     bq, bk, bv, QC, Kb, Vt, PP, pb);

    dim3 fg(S_ / 128, H_, B_);
    flash_attn<<<fg, 256, 0, stream>>>(QC, Kb, Vt, QC);

    dim3 gg(64, 8);
    gemm_out<<<gg, 256, 0, stream>>>(QC, WoT, bo, (float*)d_out);
}